// Round 4
// baseline (76.170 us; speedup 1.0000x reference)
//
#include <hip/hip_runtime.h>

typedef _Float16 half8 __attribute__((ext_vector_type(8)));
typedef float f32x4 __attribute__((ext_vector_type(4)));

#define DD 128

// Workspace layout:
//   FRAG: nch records of 8192 B. Record c, octet idx=(s*2+hl) in 0..7 at
//         offset idx*1024 + lane*16: 8 f16 of code n=c*16+(lane&15),
//         k = s*32 + (lane>>4)*8 + 0..7.  hl=0 -> hi half, hl=1 -> lo half.
//   E2NEG (after FRAG): nch * 256 B. Record c, lane slot = float
//         -(||e_n||^2) for n = c*16 + (lane&15)  (replicated over lane>>4).

__global__ void prep_frags_kernel(const float* __restrict__ embed,
                                  char* __restrict__ frag, int total) {
  int t = blockIdx.x * blockDim.x + threadIdx.x;
  if (t >= total) return;
  int lane = t & 63;
  int idx = (t >> 6) & 7;
  int c = t >> 9;
  int s = idx >> 1;
  int hl = idx & 1;
  int n = c * 16 + (lane & 15);
  int kb = s * 32 + ((lane >> 4) << 3);
  const float* src = embed + (size_t)n * DD + kb;
  _Float16* dst = (_Float16*)(frag + (size_t)c * 8192 + idx * 1024 + lane * 16);
#pragma unroll
  for (int j = 0; j < 8; ++j) {
    float v = src[j];
    _Float16 hi = (_Float16)v;
    dst[j] = hl ? (_Float16)(v - (float)hi) : hi;
  }
}

__global__ void prep_e2_kernel(const float* __restrict__ embed,
                               float* __restrict__ e2neg, int total) {
  int t = blockIdx.x * blockDim.x + threadIdx.x;
  if (t >= total) return;
  int lane = t & 63;
  int c = t >> 6;
  int n = c * 16 + (lane & 15);
  const float* src = embed + (size_t)n * DD;
  double s = 0.0;
  for (int j = 0; j < DD; ++j) { double v = (double)src[j]; s += v * v; }
  e2neg[c * 64 + lane] = (float)(-s);
}

// ---------------------------------------------------------------------------
// Main: block = 256 thr (4 waves), block owns 64 rows, split-K over codes:
//   wave w: rows [blk*64 + (w&1)*32, +32), codes [(w>>1)*K/2, +K/2).
// Grid = N/64 blocks -> 4 blocks/CU -> 4 waves/SIMD (vs 2 in round 2).
// Inner loop identical to round 2 (2-deep ping-pong, compiler-friendly):
// per 16-code chunk 24x mfma_f32_16x16x32_f16 (3-term f16 hi/lo split x
// 2 row-tiles), fp32 score = fmaf(2, acc, -e2), running argmax.
// LDS merge of the two K-halves, then 16-lane shuffle reduce.
// C/D layout (verified): col=lane&15, row=(lane>>4)*4+reg.
// ---------------------------------------------------------------------------
__global__ __launch_bounds__(256) void vq_argmin_kernel(
    const float* __restrict__ x, const float* __restrict__ embed,
    const char* __restrict__ wsf, const float* __restrict__ wse,
    float* __restrict__ out_q, float* __restrict__ out_i, int nch) {
  const int lane = threadIdx.x & 63;
  const int w = threadIdx.x >> 6;
  const int m16 = lane & 15;
  const int g = lane >> 4;
  const int row0 = blockIdx.x * 64 + (w & 1) * 32;
  const int kh = w >> 1;
  const int nc2 = nch >> 1;

  __shared__ float vbuf[2][64][8];
  __shared__ int ibuf[2][64][8];

  // A fragments for 2 row-tiles, f16 hi/lo split
  half8 ah[2][4], al[2][4];
#pragma unroll
  for (int t = 0; t < 2; ++t) {
    const float* xrow = x + (size_t)(row0 + t * 16 + m16) * DD;
#pragma unroll
    for (int s = 0; s < 4; ++s) {
      const float* p = xrow + s * 32 + g * 8;
      f32x4 v0 = *(const f32x4*)(p);
      f32x4 v1 = *(const f32x4*)(p + 4);
#pragma unroll
      for (int j = 0; j < 4; ++j) {
        float v = v0[j];
        _Float16 hi = (_Float16)v;
        ah[t][s][j] = hi;
        al[t][s][j] = (_Float16)(v - (float)hi);
      }
#pragma unroll
      for (int j = 0; j < 4; ++j) {
        float v = v1[j];
        _Float16 hi = (_Float16)v;
        ah[t][s][4 + j] = hi;
        al[t][s][4 + j] = (_Float16)(v - (float)hi);
      }
    }
  }

  float bestv0[4], bestv1[4];
  int besti0[4], besti1[4];
#pragma unroll
  for (int r = 0; r < 4; ++r) {
    bestv0[r] = -__builtin_inff();
    bestv1[r] = -__builtin_inff();
    besti0[r] = 0;
    besti1[r] = 0;
  }

  half8 bhA[4], blA[4], bhB[4], blB[4];
  float neA, neB;

#define LOADB(BH, BL, NE, C)                                        \
  do {                                                              \
    const char* pf = wsf + (size_t)(C)*8192 + lane * 16;            \
    const char* pf1 = pf + 4096;                                    \
    BH[0] = *(const half8*)(pf);                                    \
    BL[0] = *(const half8*)(pf + 1024);                             \
    BH[1] = *(const half8*)(pf + 2048);                             \
    BL[1] = *(const half8*)(pf + 3072);                             \
    BH[2] = *(const half8*)(pf1);                                   \
    BL[2] = *(const half8*)(pf1 + 1024);                            \
    BH[3] = *(const half8*)(pf1 + 2048);                            \
    BL[3] = *(const half8*)(pf1 + 3072);                            \
    NE = wse[(size_t)(C)*64 + lane];                                \
  } while (0)

#define COMPUTE(BH, BL, NE, C)                                               \
  do {                                                                       \
    f32x4 acc0 = {0.f, 0.f, 0.f, 0.f};                                       \
    f32x4 acc1 = {0.f, 0.f, 0.f, 0.f};                                       \
    _Pragma("unroll") for (int s = 0; s < 4; ++s) {                          \
      acc0 = __builtin_amdgcn_mfma_f32_16x16x32_f16(ah[0][s], BH[s], acc0,   \
                                                    0, 0, 0);                \
      acc1 = __builtin_amdgcn_mfma_f32_16x16x32_f16(ah[1][s], BH[s], acc1,   \
                                                    0, 0, 0);                \
      acc0 = __builtin_amdgcn_mfma_f32_16x16x32_f16(al[0][s], BH[s], acc0,   \
                                                    0, 0, 0);                \
      acc1 = __builtin_amdgcn_mfma_f32_16x16x32_f16(al[1][s], BH[s], acc1,   \
                                                    0, 0, 0);                \
      acc0 = __builtin_amdgcn_mfma_f32_16x16x32_f16(ah[0][s], BL[s], acc0,   \
                                                    0, 0, 0);                \
      acc1 = __builtin_amdgcn_mfma_f32_16x16x32_f16(ah[1][s], BL[s], acc1,   \
                                                    0, 0, 0);                \
    }                                                                        \
    const int n_ = (C)*16 + m16;                                             \
    _Pragma("unroll") for (int r = 0; r < 4; ++r) {                          \
      float s0 = fmaf(2.f, acc0[r], NE);                                     \
      if (s0 > bestv0[r]) { bestv0[r] = s0; besti0[r] = n_; }                \
      float s1 = fmaf(2.f, acc1[r], NE);                                     \
      if (s1 > bestv1[r]) { bestv1[r] = s1; besti1[r] = n_; }                \
    }                                                                        \
  } while (0)

  // this wave's half of the chunk range, round-2 ping-pong (nc2 is even)
  const int c0 = kh * nc2;
  const int cE = c0 + nc2;
  LOADB(bhA, blA, neA, c0);
  for (int c = c0; c < cE; c += 2) {
    LOADB(bhB, blB, neB, c + 1);
    COMPUTE(bhA, blA, neA, c);
    if (c + 2 < cE) LOADB(bhA, blA, neA, c + 2);
    COMPUTE(bhB, blB, neB, c + 1);
  }
#undef LOADB
#undef COMPUTE

  // cross-wave merge of the two K-halves (waves 2,3 publish to LDS)
  if (w >= 2) {
#pragma unroll
    for (int r = 0; r < 4; ++r) {
      vbuf[w - 2][lane][r] = bestv0[r];
      vbuf[w - 2][lane][4 + r] = bestv1[r];
      ibuf[w - 2][lane][r] = besti0[r];
      ibuf[w - 2][lane][4 + r] = besti1[r];
    }
  }
  __syncthreads();
  if (w >= 2) return;

#pragma unroll
  for (int r = 0; r < 4; ++r) {
    float pv0 = vbuf[w][lane][r];
    int pi0 = ibuf[w][lane][r];
    if (pv0 > bestv0[r] || (pv0 == bestv0[r] && pi0 < besti0[r])) {
      bestv0[r] = pv0;
      besti0[r] = pi0;
    }
    float pv1 = vbuf[w][lane][4 + r];
    int pi1 = ibuf[w][lane][4 + r];
    if (pv1 > bestv1[r] || (pv1 == bestv1[r] && pi1 < besti1[r])) {
      bestv1[r] = pv1;
      besti1[r] = pi1;
    }
  }

  // reduce across the 16 lanes sharing each C row; smaller index on tie
#pragma unroll
  for (int off = 1; off < 16; off <<= 1) {
#pragma unroll
    for (int r = 0; r < 4; ++r) {
      float ov0 = __shfl_xor(bestv0[r], off, 64);
      int oi0 = __shfl_xor(besti0[r], off, 64);
      if (ov0 > bestv0[r] || (ov0 == bestv0[r] && oi0 < besti0[r])) {
        bestv0[r] = ov0;
        besti0[r] = oi0;
      }
      float ov1 = __shfl_xor(bestv1[r], off, 64);
      int oi1 = __shfl_xor(besti1[r], off, 64);
      if (ov1 > bestv1[r] || (ov1 == bestv1[r] && oi1 < besti1[r])) {
        bestv1[r] = ov1;
        besti1[r] = oi1;
      }
    }
  }

  // outputs: index (as float) + gathered code row (16 lanes x 8 floats)
#pragma unroll
  for (int t = 0; t < 2; ++t) {
#pragma unroll
    for (int r = 0; r < 4; ++r) {
      const int row = row0 + t * 16 + g * 4 + r;
      const int idx = t ? besti1[r] : besti0[r];
      if (m16 == 0) out_i[row] = (float)idx;
      const f32x4* src = (const f32x4*)(embed + (size_t)idx * DD) + m16 * 2;
      f32x4* dst = (f32x4*)(out_q + (size_t)row * DD) + m16 * 2;
      dst[0] = src[0];
      dst[1] = src[1];
    }
  }
}

// ---------------------------------------------------------------------------
// Fallback: exact double-precision distance, thread per row.
// ---------------------------------------------------------------------------
__global__ void vq_fallback_kernel(const float* __restrict__ x,
                                   const float* __restrict__ embed,
                                   float* __restrict__ out_q,
                                   float* __restrict__ out_i, int N, int K) {
  int row = blockIdx.x * blockDim.x + threadIdx.x;
  if (row >= N) return;
  const float* xr = x + (size_t)row * DD;
  float xv[DD];
  for (int j = 0; j < DD; ++j) xv[j] = xr[j];
  double best = -1e300;
  int bi = 0;
  for (int k = 0; k < K; ++k) {
    const float* e = embed + (size_t)k * DD;
    double acc = 0.0;
    for (int j = 0; j < DD; ++j) {
      double d = (double)xv[j] - (double)e[j];
      acc += d * d;
    }
    double sc = -acc;
    if (sc > best) { best = sc; bi = k; }
  }
  out_i[row] = (float)bi;
  for (int j = 0; j < DD; ++j)
    out_q[(size_t)row * DD + j] = embed[(size_t)bi * DD + j];
}

extern "C" void kernel_launch(void* const* d_in, const int* in_sizes, int n_in,
                              void* d_out, int out_size, void* d_ws,
                              size_t ws_size, hipStream_t stream) {
  const float* x = (const float*)d_in[0];
  const float* embed = (const float*)d_in[1];
  const int N = in_sizes[0] / DD;  // 65536 rows
  const int K = in_sizes[1] / DD;  // 1024 codes
  float* out_q = (float*)d_out;
  float* out_i = out_q + (size_t)N * DD;

  const int nch = K / 16;
  const size_t frag_bytes = (size_t)nch * 8192;
  const size_t e2_bytes = (size_t)nch * 256;
  const size_t need = frag_bytes + e2_bytes;

  // split-K needs nch even with even half (ping-pong), rows in blocks of 64
  if (ws_size < need || (N % 64) != 0 || (K % 16) != 0 || (nch % 4) != 0) {
    vq_fallback_kernel<<<(N + 255) / 256, 256, 0, stream>>>(x, embed, out_q,
                                                            out_i, N, K);
    return;
  }

  char* wsf = (char*)d_ws;
  float* wse = (float*)(wsf + frag_bytes);

  const int total_f = nch * 8 * 64;
  prep_frags_kernel<<<(total_f + 255) / 256, 256, 0, stream>>>(embed, wsf,
                                                               total_f);
  const int total_e = nch * 64;
  prep_e2_kernel<<<(total_e + 255) / 256, 256, 0, stream>>>(embed, wse,
                                                            total_e);
  vq_argmin_kernel<<<N / 64, 256, 0, stream>>>(x, embed, wsf, wse, out_q,
                                               out_i, nch);
}

// Round 6
// 65.203 us; speedup vs baseline: 1.1682x; 1.1682x over previous
//
#include <hip/hip_runtime.h>

typedef _Float16 half8 __attribute__((ext_vector_type(8)));
typedef float f32x4 __attribute__((ext_vector_type(4)));
typedef unsigned int u32x4 __attribute__((ext_vector_type(4)));

#define DD 128

// Workspace layout:
//   FRAG: nch records of 8192 B. Record c, octet idx=(s*2+hl) in 0..7 at
//         offset idx*1024 + lane*16: 8 f16 of code n=c*16+(lane&15),
//         k = s*32 + (lane>>4)*8 + 0..7.  hl=0 -> hi half, hl=1 -> lo half.
//   E2NEG (after FRAG): nch * 256 B. Record c, lane slot = float
//         -(||e_n||^2) for n = c*16 + (lane&15)  (replicated over lane>>4).

__global__ void prep_kernel(const float* __restrict__ embed,
                            char* __restrict__ frag,
                            float* __restrict__ e2neg, int total) {
  int t = blockIdx.x * blockDim.x + threadIdx.x;
  if (t >= total) return;
  int lane = t & 63;
  int idx = (t >> 6) & 7;
  int c = t >> 9;
  int s = idx >> 1;
  int hl = idx & 1;
  int n = c * 16 + (lane & 15);
  int kb = s * 32 + ((lane >> 4) << 3);
  const float* src = embed + (size_t)n * DD + kb;
  _Float16* dst = (_Float16*)(frag + (size_t)c * 8192 + idx * 1024 + lane * 16);
#pragma unroll
  for (int j = 0; j < 8; ++j) {
    float v = src[j];
    _Float16 hi = (_Float16)v;
    dst[j] = hl ? (_Float16)(v - (float)hi) : hi;
  }
  if (idx == 0) {  // fused ||e||^2 (4 replicas per code write same value)
    const float* e = embed + (size_t)n * DD;
    double acc = 0.0;
    for (int j = 0; j < DD; ++j) { double v = (double)e[j]; acc += v * v; }
    e2neg[c * 64 + lane] = (float)(-acc);
  }
}

// ---------------------------------------------------------------------------
// Main: block = 256 thr (4 waves), block owns 128 rows (wave w: 32 rows).
// All 4 waves scan all chunks; each chunk's 8 KB fragment record is staged
// ONCE per block into LDS (reg-staged: global_load_dwordx4 -> VGPR ->
// ds_write_b128; wave w stages bytes [w*2048, +2048)), double-buffered,
// ONE barrier per chunk. Cuts L2 B-traffic 4x vs round 2 (the measured
// binding pipe: 1.07 GB @ ~17 TB/s). e2 is read directly from global
// (64 B/wave/chunk, L2-trivial).
// Per chunk per wave: 8x ds_read_b128 (conflict-free: lane*16 contiguous),
// 24x mfma_f32_16x16x32_f16 (3-term f16 hi/lo split x 2 row-tiles),
// fp32 score = fmaf(2, acc, -e2), running argmax.
// C/D layout (verified): col=lane&15, row=(lane>>4)*4+reg.
// ---------------------------------------------------------------------------
__global__ __launch_bounds__(256) void vq_argmin_kernel(
    const float* __restrict__ x, const float* __restrict__ embed,
    const char* __restrict__ wsf, const float* __restrict__ wse,
    float* __restrict__ out_q, float* __restrict__ out_i, int nch) {
  const int lane = threadIdx.x & 63;
  const int w = threadIdx.x >> 6;
  const int m16 = lane & 15;
  const int g = lane >> 4;
  const int row0 = blockIdx.x * 128 + w * 32;

  __shared__ alignas(16) char lds[2][8192];

  // A fragments for 2 row-tiles, f16 hi/lo split
  half8 ah[2][4], al[2][4];
#pragma unroll
  for (int t = 0; t < 2; ++t) {
    const float* xrow = x + (size_t)(row0 + t * 16 + m16) * DD;
#pragma unroll
    for (int s = 0; s < 4; ++s) {
      const float* p = xrow + s * 32 + g * 8;
      f32x4 v0 = *(const f32x4*)(p);
      f32x4 v1 = *(const f32x4*)(p + 4);
#pragma unroll
      for (int j = 0; j < 4; ++j) {
        float v = v0[j];
        _Float16 hi = (_Float16)v;
        ah[t][s][j] = hi;
        al[t][s][j] = (_Float16)(v - (float)hi);
      }
#pragma unroll
      for (int j = 0; j < 4; ++j) {
        float v = v1[j];
        _Float16 hi = (_Float16)v;
        ah[t][s][4 + j] = hi;
        al[t][s][4 + j] = (_Float16)(v - (float)hi);
      }
    }
  }

  float bestv0[4], bestv1[4];
  int besti0[4], besti1[4];
#pragma unroll
  for (int r = 0; r < 4; ++r) {
    bestv0[r] = -__builtin_inff();
    bestv1[r] = -__builtin_inff();
    besti0[r] = 0;
    besti1[r] = 0;
  }

  // prologue: stage chunk 0 into buf 0
  {
    const char* gs = wsf + (size_t)0 * 8192 + w * 2048 + lane * 16;
    u32x4 s0 = *(const u32x4*)(gs);
    u32x4 s1 = *(const u32x4*)(gs + 1024);
    char* lw = &lds[0][w * 2048 + lane * 16];
    *(u32x4*)(lw) = s0;
    *(u32x4*)(lw + 1024) = s1;
  }
  __syncthreads();

  for (int c = 0; c < nch; ++c) {
    const int buf = c & 1;
    // issue next chunk's global loads early (covered by this chunk's MFMAs)
    u32x4 t0, t1;
    const bool pre = (c + 1 < nch);
    if (pre) {
      const char* gs = wsf + (size_t)(c + 1) * 8192 + w * 2048 + lane * 16;
      t0 = *(const u32x4*)(gs);
      t1 = *(const u32x4*)(gs + 1024);
    }
    const float ne_ = wse[(size_t)c * 64 + lane];

    const char* fb = &lds[buf][0];
    half8 bh[4], bl[4];
#pragma unroll
    for (int s = 0; s < 4; ++s) {
      bh[s] = *(const half8*)(fb + (2 * s) * 1024 + lane * 16);
      bl[s] = *(const half8*)(fb + (2 * s + 1) * 1024 + lane * 16);
    }

    f32x4 acc0 = {0.f, 0.f, 0.f, 0.f};
    f32x4 acc1 = {0.f, 0.f, 0.f, 0.f};
#pragma unroll
    for (int s = 0; s < 4; ++s) {
      acc0 = __builtin_amdgcn_mfma_f32_16x16x32_f16(ah[0][s], bh[s], acc0, 0,
                                                    0, 0);
      acc1 = __builtin_amdgcn_mfma_f32_16x16x32_f16(ah[1][s], bh[s], acc1, 0,
                                                    0, 0);
      acc0 = __builtin_amdgcn_mfma_f32_16x16x32_f16(al[0][s], bh[s], acc0, 0,
                                                    0, 0);
      acc1 = __builtin_amdgcn_mfma_f32_16x16x32_f16(al[1][s], bh[s], acc1, 0,
                                                    0, 0);
      acc0 = __builtin_amdgcn_mfma_f32_16x16x32_f16(ah[0][s], bl[s], acc0, 0,
                                                    0, 0);
      acc1 = __builtin_amdgcn_mfma_f32_16x16x32_f16(ah[1][s], bl[s], acc1, 0,
                                                    0, 0);
    }
    const int n_ = c * 16 + m16;
#pragma unroll
    for (int r = 0; r < 4; ++r) {
      float s0 = fmaf(2.f, acc0[r], ne_);
      if (s0 > bestv0[r]) { bestv0[r] = s0; besti0[r] = n_; }
      float s1 = fmaf(2.f, acc1[r], ne_);
      if (s1 > bestv1[r]) { bestv1[r] = s1; besti1[r] = n_; }
    }

    // write next chunk into the other buffer (reads of buf^1 finished at the
    // previous barrier; consumers wait on the barrier below)
    if (pre) {
      char* lw = &lds[buf ^ 1][w * 2048 + lane * 16];
      *(u32x4*)(lw) = t0;
      *(u32x4*)(lw + 1024) = t1;
    }
    __syncthreads();
  }

  // reduce across the 16 lanes sharing each C row; smaller index on tie
#pragma unroll
  for (int off = 1; off < 16; off <<= 1) {
#pragma unroll
    for (int r = 0; r < 4; ++r) {
      float ov0 = __shfl_xor(bestv0[r], off, 64);
      int oi0 = __shfl_xor(besti0[r], off, 64);
      if (ov0 > bestv0[r] || (ov0 == bestv0[r] && oi0 < besti0[r])) {
        bestv0[r] = ov0;
        besti0[r] = oi0;
      }
      float ov1 = __shfl_xor(bestv1[r], off, 64);
      int oi1 = __shfl_xor(besti1[r], off, 64);
      if (ov1 > bestv1[r] || (ov1 == bestv1[r] && oi1 < besti1[r])) {
        bestv1[r] = ov1;
        besti1[r] = oi1;
      }
    }
  }

  // outputs: index (as float) + gathered code row (16 lanes x 8 floats)
#pragma unroll
  for (int t = 0; t < 2; ++t) {
#pragma unroll
    for (int r = 0; r < 4; ++r) {
      const int row = row0 + t * 16 + g * 4 + r;
      const int idx = t ? besti1[r] : besti0[r];
      if (m16 == 0) out_i[row] = (float)idx;
      const f32x4* src = (const f32x4*)(embed + (size_t)idx * DD) + m16 * 2;
      f32x4* dst = (f32x4*)(out_q + (size_t)row * DD) + m16 * 2;
      dst[0] = src[0];
      dst[1] = src[1];
    }
  }
}

// ---------------------------------------------------------------------------
// Fallback: exact double-precision distance, thread per row.
// ---------------------------------------------------------------------------
__global__ void vq_fallback_kernel(const float* __restrict__ x,
                                   const float* __restrict__ embed,
                                   float* __restrict__ out_q,
                                   float* __restrict__ out_i, int N, int K) {
  int row = blockIdx.x * blockDim.x + threadIdx.x;
  if (row >= N) return;
  const float* xr = x + (size_t)row * DD;
  float xv[DD];
  for (int j = 0; j < DD; ++j) xv[j] = xr[j];
  double best = -1e300;
  int bi = 0;
  for (int k = 0; k < K; ++k) {
    const float* e = embed + (size_t)k * DD;
    double acc = 0.0;
    for (int j = 0; j < DD; ++j) {
      double d = (double)xv[j] - (double)e[j];
      acc += d * d;
    }
    double sc = -acc;
    if (sc > best) { best = sc; bi = k; }
  }
  out_i[row] = (float)bi;
  for (int j = 0; j < DD; ++j)
    out_q[(size_t)row * DD + j] = embed[(size_t)bi * DD + j];
}

extern "C" void kernel_launch(void* const* d_in, const int* in_sizes, int n_in,
                              void* d_out, int out_size, void* d_ws,
                              size_t ws_size, hipStream_t stream) {
  const float* x = (const float*)d_in[0];
  const float* embed = (const float*)d_in[1];
  const int N = in_sizes[0] / DD;  // 65536 rows
  const int K = in_sizes[1] / DD;  // 1024 codes
  float* out_q = (float*)d_out;
  float* out_i = out_q + (size_t)N * DD;

  const int nch = K / 16;
  const size_t frag_bytes = (size_t)nch * 8192;
  const size_t e2_bytes = (size_t)nch * 256;
  const size_t need = frag_bytes + e2_bytes;

  if (ws_size < need || (N % 128) != 0 || (K % 16) != 0) {
    vq_fallback_kernel<<<(N + 255) / 256, 256, 0, stream>>>(x, embed, out_q,
                                                            out_i, N, K);
    return;
  }

  char* wsf = (char*)d_ws;
  float* wse = (float*)(wsf + frag_bytes);

  const int total_f = nch * 8 * 64;
  prep_kernel<<<(total_f + 255) / 256, 256, 0, stream>>>(embed, wsf, wse,
                                                         total_f);
  vq_argmin_kernel<<<N / 128, 256, 0, stream>>>(x, embed, wsf, wse, out_q,
                                                out_i, nch);
}